// Round 1
// baseline (199.800 us; speedup 1.0000x reference)
//
#include <hip/hip_runtime.h>

#define T_TOTAL 4194304
#define BLK 256
#define PER_TH 4
#define CHUNK (BLK * PER_TH)        // 1024 elements per block
#define NB (T_TOTAL / CHUNK)        // 4096 blocks

// -------- helpers --------
__device__ __forceinline__ void f4_to_arr(float4 v, float* a) {
    a[0] = v.x; a[1] = v.y; a[2] = v.z; a[3] = v.w;
}

// Compute a[i] = terminals*min(1,ratio), d[i] = min(1,ratio)*(rew + term*nv - val)
// for the 4 elements at float4 index f4. All loads perfectly coalesced.
__device__ __forceinline__ void compute_ad(
    size_t f4,
    const float* __restrict__ lp, const float* __restrict__ olp,
    const float* __restrict__ val, const float* __restrict__ nval,
    const float* __restrict__ rew, const float* __restrict__ ter,
    float* a, float* d)
{
    float L[4], O[4], V[4], N[4], R[4], Tm[4];
    f4_to_arr(((const float4*)lp)[f4],  L);
    f4_to_arr(((const float4*)olp)[f4], O);
    f4_to_arr(((const float4*)val)[f4], V);
    f4_to_arr(((const float4*)nval)[f4],N);
    f4_to_arr(((const float4*)rew)[f4], R);
    f4_to_arr(((const float4*)ter)[f4], Tm);
#pragma unroll
    for (int i = 0; i < 4; ++i) {
        float ratio = __expf(L[i] - O[i]);
        float rho   = fminf(1.0f, ratio);
        a[i] = Tm[i] * rho;
        d[i] = rho * (R[i] + Tm[i] * N[i] - V[i]);
    }
}

// -------- pass 1: per-chunk composed transform --------
__global__ __launch_bounds__(BLK) void k_block_xform(
    const float* __restrict__ lp, const float* __restrict__ olp,
    const float* __restrict__ val, const float* __restrict__ nval,
    const float* __restrict__ rew, const float* __restrict__ ter,
    float* __restrict__ bA, float* __restrict__ bD)
{
    const int b = blockIdx.x, t = threadIdx.x;
    const size_t f4 = (size_t)b * (CHUNK / 4) + t;

    float a[4], d[4];
    compute_ad(f4, lp, olp, val, nval, rew, ter, a, d);

    // per-thread serial compose (increasing index): v[left] = A*v[right] + D
    float A = 1.0f, D = 0.0f;
#pragma unroll
    for (int i = 0; i < 4; ++i) { D += A * d[i]; A *= a[i]; }

    __shared__ float sA[BLK], sD[BLK];
    sA[t] = A; sD[t] = D;
    __syncthreads();
    // ordered adjacent-pair tree reduction: combine(slot t, slot t+s), t multiple of 2s
    for (int s = 1; s < BLK; s <<= 1) {
        if ((t & (2 * s - 1)) == 0) {
            sD[t] = sD[t] + sA[t] * sD[t + s];
            sA[t] = sA[t] * sA[t + s];
        }
        __syncthreads();
    }
    if (t == 0) { bA[b] = sA[0]; bD[b] = sD[0]; }
}

// -------- pass 2: backward scan over chunk transforms --------
__global__ __launch_bounds__(1024) void k_scan(
    const float* __restrict__ bA, const float* __restrict__ bD,
    float* __restrict__ carry, double* __restrict__ acc)
{
    const int t = threadIdx.x;
    if (t == 0) *acc = 0.0;  // zero the loss accumulator for this call

    // thread t composes 4 adjacent chunk transforms [4t .. 4t+3]
    float a[4], d[4];
    f4_to_arr(((const float4*)bA)[t], a);
    f4_to_arr(((const float4*)bD)[t], d);
    float A = 1.0f, D = 0.0f;
#pragma unroll
    for (int i = 0; i < 4; ++i) { D += A * d[i]; A *= a[i]; }

    // reversed storage: position r holds coarse group (1023 - r)
    __shared__ float sA[1024], sD[1024];
    sA[1023 - t] = A; sD[1023 - t] = D;
    __syncthreads();
    // Hillis-Steele inclusive scan; scanned[r] = compose(groups [1023-r .. 1023])
    for (int s = 1; s < 1024; s <<= 1) {
        float xa = sA[t], xd = sD[t], za = 1.0f, zd = 0.0f;
        const bool doit = (t >= s);
        if (doit) { za = sA[t - s]; zd = sD[t - s]; }
        __syncthreads();
        if (doit) { sD[t] = xd + xa * zd; sA[t] = xa * za; }
        __syncthreads();
    }

    // v at right edge of coarse group t = suffix(groups t+1..1023) applied to 0
    float vg = (t == 1023) ? 0.0f : sD[1022 - t];

    // distribute to the 4 fine chunks: carry[k] = v at right edge of chunk k
    float v = vg, c[4];
#pragma unroll
    for (int i = 3; i >= 0; --i) { c[i] = v; v = a[i] * v + d[i]; }
    ((float4*)carry)[t] = make_float4(c[0], c[1], c[2], c[3]);
}

// -------- pass 3: final recurrence + outputs --------
__global__ __launch_bounds__(BLK) void k_final(
    const float* __restrict__ lp, const float* __restrict__ olp,
    const float* __restrict__ val, const float* __restrict__ nval,
    const float* __restrict__ rew, const float* __restrict__ ter,
    const float* __restrict__ carry,
    float* __restrict__ out, double* __restrict__ acc)
{
    const int b = blockIdx.x, t = threadIdx.x;
    const size_t f4 = (size_t)b * (CHUNK / 4) + t;

    float a[4], d[4];
    compute_ad(f4, lp, olp, val, nval, rew, ter, a, d);

    float A = 1.0f, D = 0.0f;
#pragma unroll
    for (int i = 0; i < 4; ++i) { D += A * d[i]; A *= a[i]; }

    __shared__ float sA[BLK], sD[BLK];
    __shared__ float sv[CHUNK];
    sA[BLK - 1 - t] = A; sD[BLK - 1 - t] = D;
    __syncthreads();
    for (int s = 1; s < BLK; s <<= 1) {
        float xa = sA[t], xd = sD[t], za = 1.0f, zd = 0.0f;
        const bool doit = (t >= s);
        if (doit) { za = sA[t - s]; zd = sD[t - s]; }
        __syncthreads();
        if (doit) { sD[t] = xd + xa * zd; sA[t] = xa * za; }
        __syncthreads();
    }

    // carry into this thread's segment: v at element (t+1)*4 of the chunk
    const float Cb = carry[b];
    float vc;
    if (t == BLK - 1) vc = Cb;
    else { const int q = BLK - 2 - t; vc = sA[q] * Cb + sD[q]; }

    // serial backward recurrence over the 4 elements; ys[i] = v[i]
    float v = vc, o[4];
#pragma unroll
    for (int i = 3; i >= 0; --i) { v = a[i] * v + d[i]; o[i] = v; }
    float ss = o[0]*o[0] + o[1]*o[1] + o[2]*o[2] + o[3]*o[3];

    // stage in LDS, then coalesced scalar stores (out+1 is 4B-misaligned for float4)
    sv[4 * t + 0] = o[0]; sv[4 * t + 1] = o[1];
    sv[4 * t + 2] = o[2]; sv[4 * t + 3] = o[3];
    __syncthreads();
    const size_t obase = 1 + (size_t)b * CHUNK;
#pragma unroll
    for (int k = 0; k < 4; ++k) out[obase + t + k * BLK] = sv[t + k * BLK];

    // block reduction of sum of squares -> one atomic per block
    sA[t] = ss;
    __syncthreads();
    for (int s = BLK / 2; s > 0; s >>= 1) {
        if (t < s) sA[t] += sA[t + s];
        __syncthreads();
    }
    if (t == 0) atomicAdd(acc, (double)sA[0]);
}

// -------- pass 4: finalize loss --------
__global__ void k_loss(const double* __restrict__ acc, float* __restrict__ out) {
    out[0] = (float)(*acc * (1.0 / (double)T_TOTAL));
}

extern "C" void kernel_launch(void* const* d_in, const int* in_sizes, int n_in,
                              void* d_out, int out_size, void* d_ws, size_t ws_size,
                              hipStream_t stream) {
    const float* lp   = (const float*)d_in[0];
    const float* olp  = (const float*)d_in[1];
    const float* val  = (const float*)d_in[2];
    const float* nval = (const float*)d_in[3];
    const float* rew  = (const float*)d_in[4];
    const float* ter  = (const float*)d_in[5];
    float* out = (float*)d_out;

    double* acc  = (double*)d_ws;
    float* bA    = (float*)((char*)d_ws + 16);
    float* bD    = bA + NB;
    float* carry = bD + NB;   // total ws use: 16 + 3*NB*4 = ~48 KB

    k_block_xform<<<NB, BLK, 0, stream>>>(lp, olp, val, nval, rew, ter, bA, bD);
    k_scan<<<1, 1024, 0, stream>>>(bA, bD, carry, acc);
    k_final<<<NB, BLK, 0, stream>>>(lp, olp, val, nval, rew, ter, carry, out, acc);
    k_loss<<<1, 1, 0, stream>>>(acc, out);
}